// Round 13
// baseline (353.544 us; speedup 1.0000x reference)
//
#include <hip/hip_runtime.h>
#include <hip/hip_fp16.h>

typedef _Float16 f16;
typedef f16  f16x8 __attribute__((ext_vector_type(8)));
typedef f16  f16x4 __attribute__((ext_vector_type(4)));
typedef float f32x4 __attribute__((ext_vector_type(4)));

#define B_  4
#define T_  2048
#define D_  1024
#define H_  16
#define HD_ 64
#define M_  (B_*T_)   // 8192

__device__ __forceinline__ void gload_lds16(const void* g, void* l) {
    __builtin_amdgcn_global_load_lds((__attribute__((address_space(1))) void*)(g),
                                     (__attribute__((address_space(3))) void*)(l),
                                     16, 0, 0);
}

// ---------------- fp32 -> fp16 convert (vectorized) ----------------
__global__ __launch_bounds__(256) void cvt_f32_f16(const float* __restrict__ in,
                                                   f16* __restrict__ out, int n4) {
    int idx = blockIdx.x * blockDim.x + threadIdx.x;
    int stride = gridDim.x * blockDim.x;
    for (int i = idx; i < n4; i += stride) {
        float4 v = ((const float4*)in)[i];
        f16x4 o;
        o[0] = (f16)v.x; o[1] = (f16)v.y; o[2] = (f16)v.z; o[3] = (f16)v.w;
        ((f16x4*)out)[i] = o;
    }
}

// ---------------- transpose + convert: in [R][C] f32 -> out [C][R] f16 ----------------
__global__ __launch_bounds__(256) void transpose_cvt(const float* __restrict__ in,
                                                     f16* __restrict__ out, int R, int C) {
    __shared__ float tile[32][33];
    int bx = blockIdx.x * 32;   // col (n) base
    int by = blockIdx.y * 32;   // row (k) base
    int tx = threadIdx.x, ty = threadIdx.y;   // 32 x 8
    #pragma unroll
    for (int i = 0; i < 32; i += 8)
        tile[ty + i][tx] = in[(size_t)(by + ty + i) * C + bx + tx];
    __syncthreads();
    #pragma unroll
    for (int i = 0; i < 32; i += 8)
        out[(size_t)(bx + ty + i) * R + by + tx] = (f16)tile[tx][ty + i];
}

// ---------------- 128x128 BT-GEMM (m97 structure), K=1024 fixed ----------------
// EPI 0: scatter to Q (pre-scaled by 0.125*log2e), K, Vt.  EPI 1: f32 C.
template<int EPI>
__global__ __launch_bounds__(256) void gemm128(const f16* __restrict__ A,
                                               const f16* __restrict__ Bt, int N,
                                               f16* __restrict__ Qb, f16* __restrict__ Kb,
                                               f16* __restrict__ Vt, float* __restrict__ Cout) {
    __shared__ f16 At[128][32];
    __shared__ f16 Bs[128][32];
    const int tid = threadIdx.x;
    const int lane = tid & 63;
    const int w = tid >> 6;
    const int g = lane >> 4;
    const int l15 = lane & 15;
    const int wr = w >> 1, wc = w & 1;
    const int m0 = blockIdx.y * 128;
    const int n0 = blockIdx.x * 128;
    const int K = 1024;

    f32x4 acc[4][4];
    #pragma unroll
    for (int i = 0; i < 4; i++)
        #pragma unroll
        for (int j = 0; j < 4; j++)
            acc[i][j] = f32x4{0.f, 0.f, 0.f, 0.f};

    for (int k0 = 0; k0 < K; k0 += 32) {
        __syncthreads();
        #pragma unroll
        for (int i = 0; i < 2; i++) {
            int call = w * 2 + i;
            int chunk = call * 64 + lane;
            int r  = chunk >> 2;
            int c8 = (chunk & 3) * 8;
            gload_lds16(&A [(size_t)(m0 + r) * K + k0 + c8], ((char*)&At[0][0]) + (size_t)call * 1024);
            gload_lds16(&Bt[(size_t)(n0 + r) * K + k0 + c8], ((char*)&Bs[0][0]) + (size_t)call * 1024);
        }
        __syncthreads();
        f16x8 a[4], b[4];
        #pragma unroll
        for (int i = 0; i < 4; i++) a[i] = *(const f16x8*)&At[wr * 64 + i * 16 + l15][g * 8];
        #pragma unroll
        for (int j = 0; j < 4; j++) b[j] = *(const f16x8*)&Bs[wc * 64 + j * 16 + l15][g * 8];
        #pragma unroll
        for (int i = 0; i < 4; i++)
            #pragma unroll
            for (int j = 0; j < 4; j++)
                acc[i][j] = __builtin_amdgcn_mfma_f32_16x16x32_f16(a[i], b[j], acc[i][j], 0, 0, 0);
    }

    if (EPI == 0) {
        const int which = n0 >> 10;
        const int nbase = (n0 & 1023) + wc * 64;
        const float qscale = 0.18033688011112042f;   // 0.125 * log2(e), folded into Q
        #pragma unroll
        for (int i = 0; i < 4; i++) {
            int m = m0 + wr * 64 + i * 16 + g * 4;
            int bb = m >> 11;
            int t  = m & 2047;
            #pragma unroll
            for (int j = 0; j < 4; j++) {
                int n = nbase + j * 16 + l15;
                int h = n >> 6, d = n & 63;
                #pragma unroll
                for (int r = 0; r < 4; r++) {
                    if      (which == 0) Qb[(((size_t)bb * H_ + h) * T_ + t + r) * HD_ + d] = (f16)(acc[i][j][r] * qscale);
                    else if (which == 1) Kb[(((size_t)bb * H_ + h) * T_ + t + r) * HD_ + d] = (f16)acc[i][j][r];
                    else                 Vt[(((size_t)bb * H_ + h) * HD_ + d) * T_ + t + r] = (f16)acc[i][j][r];
                }
            }
        }
    } else {
        #pragma unroll
        for (int i = 0; i < 4; i++)
            #pragma unroll
            for (int j = 0; j < 4; j++)
                #pragma unroll
                for (int r = 0; r < 4; r++)
                    Cout[(size_t)(m0 + wr * 64 + i * 16 + g * 4 + r) * N + n0 + wc * 64 + j * 16 + l15]
                        = acc[i][j][r];
    }
}

// ---------------- causal flash attention v4 ----------------
// grid (8, B*H), 256 threads, 4 blocks/CU. Mirror-pair balance (uniform 34 tiles).
// K double-buffered in LDS (XOR-swizzled, global_load_lds, counted vmcnt);
// V read directly from Vt (L1/L2-resident tile, shared across waves);
// wave-uniform interior/diagonal split (mask only on diagonal tiles);
// Q pre-scaled so softmax works directly in log2 domain.
__global__ __launch_bounds__(256, 4) void attn_fwd(const f16* __restrict__ Qb, const f16* __restrict__ Kb,
                                                   const f16* __restrict__ Vt, f16* __restrict__ Yb) {
    __shared__ f16 KsB[2][64][64];   // [buf][key][d]      16 KB
    __shared__ f16 PsB[4][32][64];   // [wave][q][key]     16 KB
    const int tid = threadIdx.x;
    const int lane = tid & 63;
    const int w = tid >> 6;
    const int g = lane >> 4;
    const int l15 = lane & 15;
    const int l8 = l15 & 7;
    const int bh = blockIdx.y;
    const int b = bh >> 4, h = bh & 15;
    const int bx = blockIdx.x;                  // 0..7

    const f16* Qp = Qb + (size_t)bh * T_ * HD_;
    const f16* Kp = Kb + (size_t)bh * T_ * HD_;
    const f16* Vp = Vt + (size_t)bh * HD_ * T_;

    // stage K[k0..k0+64) into buf; source pre-swizzled (rule #21), LDS linear
    auto STAGE = [&](int buf, int it) {
        const int k0 = it * 64;
        #pragma unroll
        for (int cc = 0; cc < 2; cc++) {
            int cb = w * 2 + cc;
            int chunk = cb * 64 + lane;
            int row = chunk >> 3;              // key
            int sc = (chunk & 7) ^ (row & 7);  // swizzled 16B chunk within 128B row
            gload_lds16(&Kp[(size_t)(k0 + row) * HD_ + sc * 8],
                        (char*)&KsB[buf][0][0] + (size_t)cb * 1024);
        }
    };

    #pragma unroll 1
    for (int asg = 0; asg < 2; asg++) {
        const int qbl = asg == 0 ? 15 - bx : bx;          // heavy first, then mirror
        const int qw = qbl * 128 + w * 32;
        const int NT = 2 * qbl + 2;                       // 64-key tiles

        // Q fragments (B-operand): qf[qs][dh], col=q=l15, k=d  (Q pre-scaled)
        f16x8 qf[2][2];
        #pragma unroll
        for (int qs = 0; qs < 2; qs++)
            #pragma unroll
            for (int dh = 0; dh < 2; dh++)
                qf[qs][dh] = *(const f16x8*)&Qp[(size_t)(qw + qs * 16 + l15) * HD_ + dh * 32 + g * 8];

        f32x4 acc[2][4];
        #pragma unroll
        for (int qs = 0; qs < 2; qs++)
            #pragma unroll
            for (int j = 0; j < 4; j++) acc[qs][j] = f32x4{0.f, 0.f, 0.f, 0.f};
        float mrow[2] = {-1e30f, -1e30f}, lrow[2] = {0.f, 0.f};

        STAGE(0, 0);
        for (int it = 0; it < NT; ++it) {
            const int cur = it & 1;
            const int k0 = it * 64;
            if (it + 1 < NT) {
                STAGE(cur ^ 1, it + 1);
                asm volatile("s_waitcnt vmcnt(2)" ::: "memory");   // cur's 2 K loads landed
            } else {
                asm volatile("s_waitcnt vmcnt(0)" ::: "memory");
            }
            __builtin_amdgcn_s_barrier();          // all waves' shares of cur resident
            asm volatile("" ::: "memory");

            if (k0 < qw + 32) {                    // wave-uniform: any unmasked key?
                const char* kb = (const char*)&KsB[cur][0][0];
                char*       pb = (char*)&PsB[w][0][0];

                // S^T = K·Q^T for 64 keys x 32 q (already in log2 domain)
                float s[2][16];
                if (k0 + 63 <= qw) {
                    // interior tile: no causal mask
                    #pragma unroll
                    for (int kk = 0; kk < 4; kk++) {
                        int row = kk * 16 + l15;
                        f16x8 kf0 = *(const f16x8*)(kb + row * 128 + ((g * 16) ^ (l8 << 4)));
                        f16x8 kf1 = *(const f16x8*)(kb + row * 128 + ((64 + g * 16) ^ (l8 << 4)));
                        #pragma unroll
                        for (int qs = 0; qs < 2; qs++) {
                            f32x4 st = {0.f, 0.f, 0.f, 0.f};
                            st = __builtin_amdgcn_mfma_f32_16x16x32_f16(kf0, qf[qs][0], st, 0, 0, 0);
                            st = __builtin_amdgcn_mfma_f32_16x16x32_f16(kf1, qf[qs][1], st, 0, 0, 0);
                            #pragma unroll
                            for (int r = 0; r < 4; r++) s[qs][kk * 4 + r] = st[r];
                        }
                    }
                } else {
                    // diagonal tile: causal mask
                    #pragma unroll
                    for (int kk = 0; kk < 4; kk++) {
                        int row = kk * 16 + l15;
                        f16x8 kf0 = *(const f16x8*)(kb + row * 128 + ((g * 16) ^ (l8 << 4)));
                        f16x8 kf1 = *(const f16x8*)(kb + row * 128 + ((64 + g * 16) ^ (l8 << 4)));
                        #pragma unroll
                        for (int qs = 0; qs < 2; qs++) {
                            f32x4 st = {0.f, 0.f, 0.f, 0.f};
                            st = __builtin_amdgcn_mfma_f32_16x16x32_f16(kf0, qf[qs][0], st, 0, 0, 0);
                            st = __builtin_amdgcn_mfma_f32_16x16x32_f16(kf1, qf[qs][1], st, 0, 0, 0);
                            int q = qw + qs * 16 + l15;
                            #pragma unroll
                            for (int r = 0; r < 4; r++) {
                                int key = k0 + kk * 16 + g * 4 + r;
                                s[qs][kk * 4 + r] = (key <= q) ? st[r] : -1e30f;
                            }
                        }
                    }
                }

                // online softmax per q-subtile (all 64 lanes busy)
                float alpha[2];
                #pragma unroll
                for (int qs = 0; qs < 2; qs++) {
                    float pm = s[qs][0];
                    #pragma unroll
                    for (int u = 1; u < 16; u++) pm = fmaxf(pm, s[qs][u]);
                    pm = fmaxf(pm, __shfl_xor(pm, 16));
                    pm = fmaxf(pm, __shfl_xor(pm, 32));
                    float mnew = fmaxf(mrow[qs], pm);
                    alpha[qs] = exp2f(mrow[qs] - mnew);
                    float ps = 0.f;
                    #pragma unroll
                    for (int u = 0; u < 16; u++) { s[qs][u] = exp2f(s[qs][u] - mnew); ps += s[qs][u]; }
                    ps += __shfl_xor(ps, 16);
                    ps += __shfl_xor(ps, 32);
                    lrow[qs] = lrow[qs] * alpha[qs] + ps;
                    mrow[qs] = mnew;
                    // pack 4 f16 per key-subtile -> swizzled ds_write_b64
                    int prow = qs * 16 + l15;
                    #pragma unroll
                    for (int kk = 0; kk < 4; kk++) {
                        f16x4 pk;
                        #pragma unroll
                        for (int r = 0; r < 4; r++) pk[r] = (f16)s[qs][kk * 4 + r];
                        *(f16x4*)(pb + prow * 128 + ((kk * 32 + g * 8) ^ (l8 << 4))) = pk;
                    }
                }
                asm volatile("s_waitcnt lgkmcnt(0)" ::: "memory");   // wave-local P visible
                __builtin_amdgcn_sched_barrier(0);

                // P fragments (A-operand): row=q=l15, k=key
                f16x8 pa[2][2];
                #pragma unroll
                for (int qs = 0; qs < 2; qs++)
                    #pragma unroll
                    for (int ks = 0; ks < 2; ks++)
                        pa[qs][ks] = *(const f16x8*)(pb + (qs * 16 + l15) * 128 +
                                                     ((ks * 64 + g * 16) ^ (l8 << 4)));

                float al[2][4];
                #pragma unroll
                for (int qs = 0; qs < 2; qs++)
                    #pragma unroll
                    for (int r = 0; r < 4; r++) al[qs][r] = __shfl(alpha[qs], g * 4 + r);

                // PV: V fragments straight from global (B-operand, col=d, k=key)
                #pragma unroll
                for (int j = 0; j < 4; j++) {
                    f16x8 vf0 = *(const f16x8*)&Vp[(size_t)(j * 16 + l15) * T_ + k0 + g * 8];
                    f16x8 vf1 = *(const f16x8*)&Vp[(size_t)(j * 16 + l15) * T_ + k0 + 32 + g * 8];
                    #pragma unroll
                    for (int qs = 0; qs < 2; qs++) {
                        f32x4 aj = acc[qs][j];
                        #pragma unroll
                        for (int r = 0; r < 4; r++) aj[r] *= al[qs][r];
                        aj = __builtin_amdgcn_mfma_f32_16x16x32_f16(pa[qs][0], vf0, aj, 0, 0, 0);
                        aj = __builtin_amdgcn_mfma_f32_16x16x32_f16(pa[qs][1], vf1, aj, 0, 0, 0);
                        acc[qs][j] = aj;
                    }
                }
            }

            asm volatile("" ::: "memory");
            __builtin_amdgcn_s_barrier();          // all waves done reading cur
            asm volatile("" ::: "memory");
        }

        float li[2][4];
        #pragma unroll
        for (int qs = 0; qs < 2; qs++)
            #pragma unroll
            for (int r = 0; r < 4; r++) li[qs][r] = __shfl(lrow[qs], g * 4 + r);
        #pragma unroll
        for (int qs = 0; qs < 2; qs++)
            #pragma unroll
            for (int j = 0; j < 4; j++)
                #pragma unroll
                for (int r = 0; r < 4; r++) {
                    float y = acc[qs][j][r] / li[qs][r];
                    Yb[((size_t)b * T_ + qw + qs * 16 + g * 4 + r) * D_ + h * HD_ + j * 16 + l15] = (f16)y;
                }
    }
}

// ---------------- launch ----------------
extern "C" void kernel_launch(void* const* d_in, const int* in_sizes, int n_in,
                              void* d_out, int out_size, void* d_ws, size_t ws_size,
                              hipStream_t stream) {
    const float* x      = (const float*)d_in[0];
    const float* w_qkv  = (const float*)d_in[1];
    const float* w_out  = (const float*)d_in[2];
    float* out = (float*)d_out;

    char* ws = (char*)d_ws;
    f16* Xb  = (f16*)(ws);                     // [8192][1024]            16.78 MB
    f16* Wqt = (f16*)(ws + 16777216);          // [3072][1024]             6.29 MB
    f16* Wot = (f16*)(ws + 23068672);          // [1024][1024]             2.10 MB
    f16* Qb  = (f16*)(ws + 25165824);          // [B,H,T,HD]              16.78 MB
    f16* Kb  = (f16*)(ws + 41943040);          // [B,H,T,HD]              16.78 MB
    f16* Vt  = (f16*)(ws + 58720256);          // [B,H,HD,T]              16.78 MB
    f16* Yb  = (f16*)(ws + 75497472);          // [8192][1024]            16.78 MB

    cvt_f32_f16<<<2048, 256, 0, stream>>>(x, Xb, (M_ * D_) / 4);
    transpose_cvt<<<dim3(3 * D_ / 32, D_ / 32), dim3(32, 8), 0, stream>>>(w_qkv, Wqt, D_, 3 * D_);
    transpose_cvt<<<dim3(D_ / 32, D_ / 32),     dim3(32, 8), 0, stream>>>(w_out, Wot, D_, D_);

    gemm128<0><<<dim3(3 * D_ / 128, M_ / 128), 256, 0, stream>>>(Xb, Wqt, 3 * D_, Qb, Kb, Vt, nullptr);
    attn_fwd<<<dim3(8, B_ * H_), 256, 0, stream>>>(Qb, Kb, Vt, Yb);
    gemm128<1><<<dim3(D_ / 128, M_ / 128), 256, 0, stream>>>(Yb, Wot, D_, nullptr, nullptr, nullptr, out);
}